// Round 1
// baseline (1049.776 us; speedup 1.0000x reference)
//
#include <hip/hip_runtime.h>
#include <hip/hip_bf16.h>
#include <math.h>

#define IGNORE_INDEX (-100)

constexpr int BT = 2048, H = 4096, V = 32000;
constexpr int BM = 128, BN = 128, BK = 64;
constexpr int KT = H / BK;        // 64 k-tiles
constexpr int MT = BT / BM;       // 16
constexpr int NTT = V / BN;       // 250
constexpr int NCHUNK = NTT * 2;   // 500 partial chunks per row (64 cols each)

typedef __bf16 bf16x8 __attribute__((ext_vector_type(8)));
typedef float f32x4 __attribute__((ext_vector_type(4)));

// short-unit index into a [rows][BK] bf16 LDS tile with 16B-slot XOR swizzle.
// row stride = 128B (8 slots); swizzle spreads same-slot column reads across
// banks: 2-way residual conflict = free (m136).
__device__ __forceinline__ int lds_idx(int row, int slot) {
  return row * BK + (((slot ^ (row & 7)) & 7) << 3);
}

__global__ __launch_bounds__(256, 2)
void fused_gemm_lse(const float* __restrict__ Wt,   // (V,H) row-major = B^T
                    const float* __restrict__ X,    // (BT,H)
                    const int* __restrict__ target,
                    const float* __restrict__ bias,
                    float* __restrict__ pM, float* __restrict__ pS,
                    float* __restrict__ gold)
{
  __shared__ short As[2][BM * BK];
  __shared__ short Ws[2][BN * BK];

  const int tid = threadIdx.x;
  const int lane = tid & 63;
  const int wid = tid >> 6;
  const int wr = wid >> 1;          // wave row (0..1): rows [wr*64, +64)
  const int wc = wid & 1;           // wave col (0..1): cols [wc*64, +64)

  const int mt = blockIdx.x & (MT - 1);
  const int nt = blockIdx.x >> 4;   // consecutive blocks share the W panel
  const int m0 = mt * BM, n0 = nt * BN;

  // staging decomposition: per load-instr a wave covers 8 rows x 64 floats
  const int l8 = lane & 7;          // float col group [l8*8, +8)
  const int r8 = lane >> 3;         // row within 8-row group

  f32x4 acc[4][4] = {};

  float4 ra[8], rw[8];              // prefetch regs: 4 row-iters x 2 float4

#define LOAD_TILE(KTI)                                                        \
  {                                                                           \
    const int kb = (KTI) * BK;                                                \
    _Pragma("unroll")                                                         \
    for (int i = 0; i < 4; ++i) {                                             \
      const int row = wid * 32 + i * 8 + r8;                                  \
      const float* pa = X + (size_t)(m0 + row) * H + kb + l8 * 8;             \
      const float* pw = Wt + (size_t)(n0 + row) * H + kb + l8 * 8;            \
      ra[2 * i] = *(const float4*)pa;                                         \
      ra[2 * i + 1] = *(const float4*)(pa + 4);                               \
      rw[2 * i] = *(const float4*)pw;                                         \
      rw[2 * i + 1] = *(const float4*)(pw + 4);                               \
    }                                                                         \
  }

#define WRITE_TILE(BUF)                                                       \
  {                                                                           \
    _Pragma("unroll")                                                         \
    for (int i = 0; i < 4; ++i) {                                             \
      const int row = wid * 32 + i * 8 + r8;                                  \
      const int idx = lds_idx(row, l8);                                       \
      bf16x8 va, vw;                                                          \
      float4 f0 = ra[2 * i], f1 = ra[2 * i + 1];                              \
      va[0] = (__bf16)f0.x; va[1] = (__bf16)f0.y;                             \
      va[2] = (__bf16)f0.z; va[3] = (__bf16)f0.w;                             \
      va[4] = (__bf16)f1.x; va[5] = (__bf16)f1.y;                             \
      va[6] = (__bf16)f1.z; va[7] = (__bf16)f1.w;                             \
      f0 = rw[2 * i]; f1 = rw[2 * i + 1];                                     \
      vw[0] = (__bf16)f0.x; vw[1] = (__bf16)f0.y;                             \
      vw[2] = (__bf16)f0.z; vw[3] = (__bf16)f0.w;                             \
      vw[4] = (__bf16)f1.x; vw[5] = (__bf16)f1.y;                             \
      vw[6] = (__bf16)f1.z; vw[7] = (__bf16)f1.w;                             \
      *(bf16x8*)&As[BUF][idx] = va;                                           \
      *(bf16x8*)&Ws[BUF][idx] = vw;                                           \
    }                                                                         \
  }

#define COMPUTE(BUF)                                                          \
  {                                                                           \
    _Pragma("unroll")                                                         \
    for (int kk = 0; kk < 2; ++kk) {                                          \
      bf16x8 af[4], bfr[4];                                                   \
      const int slot = kk * 4 + (lane >> 4);                                  \
      _Pragma("unroll")                                                       \
      for (int mi = 0; mi < 4; ++mi) {                                        \
        const int row = wr * 64 + mi * 16 + (lane & 15);                      \
        af[mi] = *(const bf16x8*)&As[BUF][lds_idx(row, slot)];                \
      }                                                                       \
      _Pragma("unroll")                                                       \
      for (int ni = 0; ni < 4; ++ni) {                                        \
        const int row = wc * 64 + ni * 16 + (lane & 15);                      \
        bfr[ni] = *(const bf16x8*)&Ws[BUF][lds_idx(row, slot)];               \
      }                                                                       \
      _Pragma("unroll")                                                       \
      for (int mi = 0; mi < 4; ++mi)                                          \
        _Pragma("unroll")                                                     \
        for (int ni = 0; ni < 4; ++ni)                                        \
          acc[mi][ni] = __builtin_amdgcn_mfma_f32_16x16x32_bf16(              \
              af[mi], bfr[ni], acc[mi][ni], 0, 0, 0);                         \
    }                                                                         \
  }

  // prologue
  LOAD_TILE(0);
  WRITE_TILE(0);
  __syncthreads();

  int cur = 0;
  for (int kt = 0; kt < KT; ++kt) {
    if (kt + 1 < KT) LOAD_TILE(kt + 1);   // issue next-tile loads early
    COMPUTE(cur);                          // ds_read + MFMA on current buf
    if (kt + 1 < KT) WRITE_TILE(cur ^ 1);  // cvt + ds_write next buf
    __syncthreads();
    cur ^= 1;
  }

  // ---------- epilogue: bias + per-row (max, sum-exp) over this wave's 64 cols
  const int g = lane >> 4;      // row group
  const int c = lane & 15;      // col-in-fragment
  const int colbase = n0 + wc * 64;
  float bv[4];
#pragma unroll
  for (int ni = 0; ni < 4; ++ni) bv[ni] = bias[colbase + ni * 16 + c];

  const int chunk = nt * 2 + wc;
#pragma unroll
  for (int mi = 0; mi < 4; ++mi) {
#pragma unroll
    for (int r = 0; r < 4; ++r) {
      const int row = m0 + wr * 64 + mi * 16 + g * 4 + r;
      const float v0 = acc[mi][0][r] + bv[0];
      const float v1 = acc[mi][1][r] + bv[1];
      const float v2 = acc[mi][2][r] + bv[2];
      const float v3 = acc[mi][3][r] + bv[3];
      float mx = fmaxf(fmaxf(v0, v1), fmaxf(v2, v3));
#pragma unroll
      for (int d = 1; d < 16; d <<= 1) mx = fmaxf(mx, __shfl_xor(mx, d));
      float s = expf(v0 - mx) + expf(v1 - mx) + expf(v2 - mx) + expf(v3 - mx);
#pragma unroll
      for (int d = 1; d < 16; d <<= 1) s += __shfl_xor(s, d);
      if (c == 0) {
        pM[(size_t)row * NCHUNK + chunk] = mx;
        pS[(size_t)row * NCHUNK + chunk] = s;
      }
      const int t = target[row];
      const int d0 = t - colbase;
      if (d0 >= 0 && d0 < 64 && c == (d0 & 15)) {
        const int nw = d0 >> 4;
        const float gv = (nw == 0) ? v0 : (nw == 1) ? v1 : (nw == 2) ? v2 : v3;
        gold[row] = gv;
      }
    }
  }
#undef LOAD_TILE
#undef WRITE_TILE
#undef COMPUTE
}

// one wave per row: combine 500 (max, sumexp) chunks -> rowterm
__global__ __launch_bounds__(256)
void reduce_lse(const float* __restrict__ pM, const float* __restrict__ pS,
                const float* __restrict__ gold, const int* __restrict__ target,
                const float* __restrict__ lw, float* __restrict__ rowterm)
{
  const int wid = threadIdx.x >> 6, lane = threadIdx.x & 63;
  const int row = blockIdx.x * 4 + wid;
  if (row >= BT) return;
  const float* pm = pM + (size_t)row * NCHUNK;
  const float* ps = pS + (size_t)row * NCHUNK;
  float m = -INFINITY;
  for (int c2 = lane; c2 < NCHUNK; c2 += 64) m = fmaxf(m, pm[c2]);
#pragma unroll
  for (int d = 1; d < 64; d <<= 1) m = fmaxf(m, __shfl_xor(m, d));
  float s = 0.f;
  for (int c2 = lane; c2 < NCHUNK; c2 += 64) s += ps[c2] * expf(pm[c2] - m);
#pragma unroll
  for (int d = 1; d < 64; d <<= 1) s += __shfl_xor(s, d);
  if (lane == 0) {
    const int t = target[row];
    float term = 0.f;
    if (t != IGNORE_INDEX) term = (m + logf(s) - gold[row]) * lw[row];
    rowterm[row] = term;
  }
}

// single-block deterministic finalize
__global__ __launch_bounds__(256)
void finalize(const float* __restrict__ rowterm, const int* __restrict__ target,
              const float* __restrict__ rsw, const int* __restrict__ gas,
              float* __restrict__ out)
{
  __shared__ float sred[4];
  __shared__ int cred[4];
  const int tid = threadIdx.x;
  float s = 0.f;
  int cnt = 0;
  for (int i = tid; i < BT; i += 256) {
    s += rowterm[i];
    cnt += (target[i] != IGNORE_INDEX) ? 1 : 0;
  }
#pragma unroll
  for (int d = 1; d < 64; d <<= 1) {
    s += __shfl_xor(s, d);
    cnt += __shfl_xor(cnt, d);
  }
  const int wid = tid >> 6, lane = tid & 63;
  if (lane == 0) { sred[wid] = s; cred[wid] = cnt; }
  __syncthreads();
  if (tid == 0) {
    const float st = sred[0] + sred[1] + sred[2] + sred[3];
    const int ct = cred[0] + cred[1] + cred[2] + cred[3];
    const float n = (float)((ct > 0) ? ct : 1);
    const float rs = rsw[0];
    float loss = (rs == 0.f) ? 0.f : (st / n) / rs;
    loss /= (float)gas[0];
    out[0] = loss;
  }
}

extern "C" void kernel_launch(void* const* d_in, const int* in_sizes, int n_in,
                              void* d_out, int out_size, void* d_ws, size_t ws_size,
                              hipStream_t stream)
{
  const float* Wt     = (const float*)d_in[0];  // lin_weight (V,H)
  const float* X      = (const float*)d_in[1];  // _input (BT,H)
  const int*   target = (const int*)d_in[2];
  const float* bias   = (const float*)d_in[3];
  const float* lw     = (const float*)d_in[4];  // loss_weights
  const float* rsw    = (const float*)d_in[5];  // reduce_sum_loss_weights
  const int*   gas    = (const int*)d_in[6];    // grad_accumulation_steps
  float* out = (float*)d_out;

  // workspace layout (~8.2 MB)
  float* pM = (float*)d_ws;                      // BT*NCHUNK
  float* pS = pM + (size_t)BT * NCHUNK;          // BT*NCHUNK
  float* gold = pS + (size_t)BT * NCHUNK;        // BT
  float* rowterm = gold + BT;                    // BT

  fused_gemm_lse<<<dim3(MT * NTT), dim3(256), 0, stream>>>(Wt, X, target, bias,
                                                           pM, pS, gold);
  reduce_lse<<<dim3(BT / 4), dim3(256), 0, stream>>>(pM, pS, gold, target, lw,
                                                     rowterm);
  finalize<<<dim3(1), dim3(256), 0, stream>>>(rowterm, target, rsw, gas, out);
}

// Round 2
// 943.598 us; speedup vs baseline: 1.1125x; 1.1125x over previous
//
#include <hip/hip_runtime.h>
#include <hip/hip_bf16.h>
#include <math.h>

#define IGNORE_INDEX (-100)

constexpr int BT = 2048, H = 4096, V = 32000;
constexpr int BM = 128, BN = 128, BK = 64;
constexpr int KT = H / BK;        // 64 k-tiles
constexpr int MT = BT / BM;       // 16
constexpr int NTT = V / BN;       // 250
constexpr int NCHUNK = NTT * 2;   // 500 partial chunks per row (64 cols each)

typedef __bf16 bf16x8 __attribute__((ext_vector_type(8)));
typedef float f32x4 __attribute__((ext_vector_type(4)));

// short-unit index into a [rows][BK] bf16 LDS tile with 16B-slot XOR swizzle.
__device__ __forceinline__ int lds_idx(int row, int slot) {
  return row * BK + (((slot ^ (row & 7)) & 7) << 3);
}

__device__ __forceinline__ void gload_lds16(const __bf16* g, short* l) {
  __builtin_amdgcn_global_load_lds(
      (const __attribute__((address_space(1))) unsigned int*)(g),
      (__attribute__((address_space(3))) unsigned int*)(l), 16, 0, 0);
}

// ---------------------------------------------------------------------------
// fp32 -> bf16 bulk convert (8 elems/thread/iter, 16B loads+stores)
// ---------------------------------------------------------------------------
__global__ __launch_bounds__(256)
void convert_bf16(const float* __restrict__ src, __bf16* __restrict__ dst,
                  int n8) {
  int i = blockIdx.x * blockDim.x + threadIdx.x;
  const int stride = gridDim.x * blockDim.x;
  for (; i < n8; i += stride) {
    const float4 f0 = ((const float4*)src)[2 * i];
    const float4 f1 = ((const float4*)src)[2 * i + 1];
    bf16x8 v;
    v[0] = (__bf16)f0.x; v[1] = (__bf16)f0.y;
    v[2] = (__bf16)f0.z; v[3] = (__bf16)f0.w;
    v[4] = (__bf16)f1.x; v[5] = (__bf16)f1.y;
    v[6] = (__bf16)f1.z; v[7] = (__bf16)f1.w;
    ((bf16x8*)dst)[i] = v;
  }
}

// ---------------------------------------------------------------------------
// bf16 MFMA GEMM (m97 structure: global_load_lds w=16, pre-swizzled source,
// XCD-aware block swizzle) + fused bias/online-LSE-partial epilogue
// ---------------------------------------------------------------------------
__global__ __launch_bounds__(256, 2)
void gemm_lse_bf16(const __bf16* __restrict__ Wb,   // (V,H) bf16
                   const __bf16* __restrict__ Xb,   // (BT,H) bf16
                   const int* __restrict__ target,
                   const float* __restrict__ bias,
                   float* __restrict__ pM, float* __restrict__ pS,
                   float* __restrict__ gold)
{
  __shared__ short As[2][BM * BK];
  __shared__ short Ws[2][BN * BK];

  const int tid = threadIdx.x;
  const int lane = tid & 63;
  const int wid = tid >> 6;
  const int wr = wid >> 1;          // wave row (0..1)
  const int wc = wid & 1;           // wave col (0..1)

  // XCD-aware swizzle: nwg = 4000, 4000 % 8 == 0 -> simple bijective remap
  const int nwg = MT * NTT;
  const int bid = (int)blockIdx.x;
  const int swz = (bid & 7) * (nwg >> 3) + (bid >> 3);
  const int mt = swz & (MT - 1);
  const int nt = swz >> 4;          // consecutive swz share the W panel
  const int m0 = mt * BM, n0 = nt * BN;

  const int r8 = lane >> 3;              // row within 8-row group
  const int gs = (lane & 7) ^ r8;        // pre-swizzled global 16B slot

  f32x4 acc[4][4] = {};

  // each wave stages 1/4 of each tile: 4 x (64 lanes x 16B = 1024B = 8 rows)
#define STAGE(BUF, KTI)                                                       \
  {                                                                           \
    const int kb = (KTI) * BK;                                                \
    _Pragma("unroll")                                                         \
    for (int j = 0; j < 4; ++j) {                                             \
      const int r = wid * 32 + j * 8 + r8;                                    \
      gload_lds16(Xb + ((size_t)(m0 + r) * H + kb + gs * 8),                  \
                  &As[BUF][(wid * 4 + j) * 512]);                             \
      gload_lds16(Wb + ((size_t)(n0 + r) * H + kb + gs * 8),                  \
                  &Ws[BUF][(wid * 4 + j) * 512]);                             \
    }                                                                         \
  }

#define COMPUTE(BUF)                                                          \
  {                                                                           \
    _Pragma("unroll")                                                         \
    for (int kk = 0; kk < 2; ++kk) {                                          \
      bf16x8 af[4], bfr[4];                                                   \
      const int slot = kk * 4 + (lane >> 4);                                  \
      _Pragma("unroll")                                                       \
      for (int mi = 0; mi < 4; ++mi) {                                        \
        const int row = wr * 64 + mi * 16 + (lane & 15);                      \
        af[mi] = *(const bf16x8*)&As[BUF][lds_idx(row, slot)];                \
      }                                                                       \
      _Pragma("unroll")                                                       \
      for (int ni = 0; ni < 4; ++ni) {                                        \
        const int row = wc * 64 + ni * 16 + (lane & 15);                      \
        bfr[ni] = *(const bf16x8*)&Ws[BUF][lds_idx(row, slot)];               \
      }                                                                       \
      _Pragma("unroll")                                                       \
      for (int mi = 0; mi < 4; ++mi)                                          \
        _Pragma("unroll")                                                     \
        for (int ni = 0; ni < 4; ++ni)                                        \
          acc[mi][ni] = __builtin_amdgcn_mfma_f32_16x16x32_bf16(              \
              af[mi], bfr[ni], acc[mi][ni], 0, 0, 0);                         \
    }                                                                         \
  }

  STAGE(0, 0);
  __syncthreads();

  int cur = 0;
  for (int kt = 0; kt < KT; ++kt) {
    if (kt + 1 < KT) STAGE(cur ^ 1, kt + 1);  // issue next-tile loads early
    COMPUTE(cur);
    __syncthreads();                          // drains vmcnt+lgkmcnt
    cur ^= 1;
  }
#undef STAGE
#undef COMPUTE

  // ---------- epilogue: bias + per-row (max, sum-exp) over this wave's 64 cols
  const int g = lane >> 4;      // row group
  const int c = lane & 15;      // col-in-fragment
  const int colbase = n0 + wc * 64;
  float bv[4];
#pragma unroll
  for (int ni = 0; ni < 4; ++ni) bv[ni] = bias[colbase + ni * 16 + c];

  const int chunk = nt * 2 + wc;
#pragma unroll
  for (int mi = 0; mi < 4; ++mi) {
#pragma unroll
    for (int r = 0; r < 4; ++r) {
      const int row = m0 + wr * 64 + mi * 16 + g * 4 + r;
      const float v0 = acc[mi][0][r] + bv[0];
      const float v1 = acc[mi][1][r] + bv[1];
      const float v2 = acc[mi][2][r] + bv[2];
      const float v3 = acc[mi][3][r] + bv[3];
      float mx = fmaxf(fmaxf(v0, v1), fmaxf(v2, v3));
#pragma unroll
      for (int d = 1; d < 16; d <<= 1) mx = fmaxf(mx, __shfl_xor(mx, d));
      float s = expf(v0 - mx) + expf(v1 - mx) + expf(v2 - mx) + expf(v3 - mx);
#pragma unroll
      for (int d = 1; d < 16; d <<= 1) s += __shfl_xor(s, d);
      if (c == 0) {
        pM[(size_t)row * NCHUNK + chunk] = mx;
        pS[(size_t)row * NCHUNK + chunk] = s;
      }
      const int t = target[row];
      const int d0 = t - colbase;
      if (d0 >= 0 && d0 < 64 && c == (d0 & 15)) {
        const int nw = d0 >> 4;
        const float gv = (nw == 0) ? v0 : (nw == 1) ? v1 : (nw == 2) ? v2 : v3;
        gold[row] = gv;
      }
    }
  }
}

// ---------------------------------------------------------------------------
// FALLBACK (round-1 verified): fused fp32->bf16 reg-staged GEMM
// ---------------------------------------------------------------------------
__global__ __launch_bounds__(256, 2)
void fused_gemm_lse(const float* __restrict__ Wt, const float* __restrict__ X,
                    const int* __restrict__ target,
                    const float* __restrict__ bias,
                    float* __restrict__ pM, float* __restrict__ pS,
                    float* __restrict__ gold)
{
  __shared__ short As[2][BM * BK];
  __shared__ short Ws[2][BN * BK];

  const int tid = threadIdx.x;
  const int lane = tid & 63;
  const int wid = tid >> 6;
  const int wr = wid >> 1;
  const int wc = wid & 1;

  const int mt = blockIdx.x & (MT - 1);
  const int nt = blockIdx.x >> 4;
  const int m0 = mt * BM, n0 = nt * BN;

  const int l8 = lane & 7;
  const int r8 = lane >> 3;

  f32x4 acc[4][4] = {};
  float4 ra[8], rw[8];

#define LOAD_TILE(KTI)                                                        \
  {                                                                           \
    const int kb = (KTI) * BK;                                                \
    _Pragma("unroll")                                                         \
    for (int i = 0; i < 4; ++i) {                                             \
      const int row = wid * 32 + i * 8 + r8;                                  \
      const float* pa = X + (size_t)(m0 + row) * H + kb + l8 * 8;             \
      const float* pw = Wt + (size_t)(n0 + row) * H + kb + l8 * 8;            \
      ra[2 * i] = *(const float4*)pa;                                         \
      ra[2 * i + 1] = *(const float4*)(pa + 4);                               \
      rw[2 * i] = *(const float4*)pw;                                         \
      rw[2 * i + 1] = *(const float4*)(pw + 4);                               \
    }                                                                         \
  }

#define WRITE_TILE(BUF)                                                       \
  {                                                                           \
    _Pragma("unroll")                                                         \
    for (int i = 0; i < 4; ++i) {                                             \
      const int row = wid * 32 + i * 8 + r8;                                  \
      const int idx = lds_idx(row, l8);                                       \
      bf16x8 va, vw;                                                          \
      float4 f0 = ra[2 * i], f1 = ra[2 * i + 1];                              \
      va[0] = (__bf16)f0.x; va[1] = (__bf16)f0.y;                             \
      va[2] = (__bf16)f0.z; va[3] = (__bf16)f0.w;                             \
      va[4] = (__bf16)f1.x; va[5] = (__bf16)f1.y;                             \
      va[6] = (__bf16)f1.z; va[7] = (__bf16)f1.w;                             \
      f0 = rw[2 * i]; f1 = rw[2 * i + 1];                                     \
      vw[0] = (__bf16)f0.x; vw[1] = (__bf16)f0.y;                             \
      vw[2] = (__bf16)f0.z; vw[3] = (__bf16)f0.w;                             \
      vw[4] = (__bf16)f1.x; vw[5] = (__bf16)f1.y;                             \
      vw[6] = (__bf16)f1.z; vw[7] = (__bf16)f1.w;                             \
      *(bf16x8*)&As[BUF][idx] = va;                                           \
      *(bf16x8*)&Ws[BUF][idx] = vw;                                           \
    }                                                                         \
  }

#define COMPUTE(BUF)                                                          \
  {                                                                           \
    _Pragma("unroll")                                                         \
    for (int kk = 0; kk < 2; ++kk) {                                          \
      bf16x8 af[4], bfr[4];                                                   \
      const int slot = kk * 4 + (lane >> 4);                                  \
      _Pragma("unroll")                                                       \
      for (int mi = 0; mi < 4; ++mi) {                                        \
        const int row = wr * 64 + mi * 16 + (lane & 15);                      \
        af[mi] = *(const bf16x8*)&As[BUF][lds_idx(row, slot)];                \
      }                                                                       \
      _Pragma("unroll")                                                       \
      for (int ni = 0; ni < 4; ++ni) {                                        \
        const int row = wc * 64 + ni * 16 + (lane & 15);                      \
        bfr[ni] = *(const bf16x8*)&Ws[BUF][lds_idx(row, slot)];               \
      }                                                                       \
      _Pragma("unroll")                                                       \
      for (int mi = 0; mi < 4; ++mi)                                          \
        _Pragma("unroll")                                                     \
        for (int ni = 0; ni < 4; ++ni)                                        \
          acc[mi][ni] = __builtin_amdgcn_mfma_f32_16x16x32_bf16(              \
              af[mi], bfr[ni], acc[mi][ni], 0, 0, 0);                         \
    }                                                                         \
  }

  LOAD_TILE(0);
  WRITE_TILE(0);
  __syncthreads();

  int cur = 0;
  for (int kt = 0; kt < KT; ++kt) {
    if (kt + 1 < KT) LOAD_TILE(kt + 1);
    COMPUTE(cur);
    if (kt + 1 < KT) WRITE_TILE(cur ^ 1);
    __syncthreads();
    cur ^= 1;
  }
#undef LOAD_TILE
#undef WRITE_TILE
#undef COMPUTE

  const int g = lane >> 4;
  const int c = lane & 15;
  const int colbase = n0 + wc * 64;
  float bv[4];
#pragma unroll
  for (int ni = 0; ni < 4; ++ni) bv[ni] = bias[colbase + ni * 16 + c];

  const int chunk = nt * 2 + wc;
#pragma unroll
  for (int mi = 0; mi < 4; ++mi) {
#pragma unroll
    for (int r = 0; r < 4; ++r) {
      const int row = m0 + wr * 64 + mi * 16 + g * 4 + r;
      const float v0 = acc[mi][0][r] + bv[0];
      const float v1 = acc[mi][1][r] + bv[1];
      const float v2 = acc[mi][2][r] + bv[2];
      const float v3 = acc[mi][3][r] + bv[3];
      float mx = fmaxf(fmaxf(v0, v1), fmaxf(v2, v3));
#pragma unroll
      for (int d = 1; d < 16; d <<= 1) mx = fmaxf(mx, __shfl_xor(mx, d));
      float s = expf(v0 - mx) + expf(v1 - mx) + expf(v2 - mx) + expf(v3 - mx);
#pragma unroll
      for (int d = 1; d < 16; d <<= 1) s += __shfl_xor(s, d);
      if (c == 0) {
        pM[(size_t)row * NCHUNK + chunk] = mx;
        pS[(size_t)row * NCHUNK + chunk] = s;
      }
      const int t = target[row];
      const int d0 = t - colbase;
      if (d0 >= 0 && d0 < 64 && c == (d0 & 15)) {
        const int nw = d0 >> 4;
        const float gv = (nw == 0) ? v0 : (nw == 1) ? v1 : (nw == 2) ? v2 : v3;
        gold[row] = gv;
      }
    }
  }
}

// one wave per row: combine 500 (max, sumexp) chunks -> rowterm
__global__ __launch_bounds__(256)
void reduce_lse(const float* __restrict__ pM, const float* __restrict__ pS,
                const float* __restrict__ gold, const int* __restrict__ target,
                const float* __restrict__ lw, float* __restrict__ rowterm)
{
  const int wid = threadIdx.x >> 6, lane = threadIdx.x & 63;
  const int row = blockIdx.x * 4 + wid;
  if (row >= BT) return;
  const float* pm = pM + (size_t)row * NCHUNK;
  const float* ps = pS + (size_t)row * NCHUNK;
  float m = -INFINITY;
  for (int c2 = lane; c2 < NCHUNK; c2 += 64) m = fmaxf(m, pm[c2]);
#pragma unroll
  for (int d = 1; d < 64; d <<= 1) m = fmaxf(m, __shfl_xor(m, d));
  float s = 0.f;
  for (int c2 = lane; c2 < NCHUNK; c2 += 64) s += ps[c2] * expf(pm[c2] - m);
#pragma unroll
  for (int d = 1; d < 64; d <<= 1) s += __shfl_xor(s, d);
  if (lane == 0) {
    const int t = target[row];
    float term = 0.f;
    if (t != IGNORE_INDEX) term = (m + logf(s) - gold[row]) * lw[row];
    rowterm[row] = term;
  }
}

// single-block deterministic finalize
__global__ __launch_bounds__(256)
void finalize(const float* __restrict__ rowterm, const int* __restrict__ target,
              const float* __restrict__ rsw, const int* __restrict__ gas,
              float* __restrict__ out)
{
  __shared__ float sred[4];
  __shared__ int cred[4];
  const int tid = threadIdx.x;
  float s = 0.f;
  int cnt = 0;
  for (int i = tid; i < BT; i += 256) {
    s += rowterm[i];
    cnt += (target[i] != IGNORE_INDEX) ? 1 : 0;
  }
#pragma unroll
  for (int d = 1; d < 64; d <<= 1) {
    s += __shfl_xor(s, d);
    cnt += __shfl_xor(cnt, d);
  }
  const int wid = tid >> 6, lane = tid & 63;
  if (lane == 0) { sred[wid] = s; cred[wid] = cnt; }
  __syncthreads();
  if (tid == 0) {
    const float st = sred[0] + sred[1] + sred[2] + sred[3];
    const int ct = cred[0] + cred[1] + cred[2] + cred[3];
    const float n = (float)((ct > 0) ? ct : 1);
    const float rs = rsw[0];
    float loss = (rs == 0.f) ? 0.f : (st / n) / rs;
    loss /= (float)gas[0];
    out[0] = loss;
  }
}

extern "C" void kernel_launch(void* const* d_in, const int* in_sizes, int n_in,
                              void* d_out, int out_size, void* d_ws, size_t ws_size,
                              hipStream_t stream)
{
  const float* Wt     = (const float*)d_in[0];  // lin_weight (V,H)
  const float* X      = (const float*)d_in[1];  // _input (BT,H)
  const int*   target = (const int*)d_in[2];
  const float* bias   = (const float*)d_in[3];
  const float* lw     = (const float*)d_in[4];
  const float* rsw    = (const float*)d_in[5];
  const int*   gas    = (const int*)d_in[6];
  float* out = (float*)d_out;

  const size_t nW = (size_t)V * H, nX = (size_t)BT * H;
  const size_t needFast = nW * 2 + nX * 2 +
                          2 * (size_t)BT * NCHUNK * 4 + 2 * (size_t)BT * 4;

  if (ws_size >= needFast) {
    __bf16* Wb = (__bf16*)d_ws;
    __bf16* Xb = Wb + nW;
    float* pM = (float*)(Xb + nX);
    float* pS = pM + (size_t)BT * NCHUNK;
    float* gold = pS + (size_t)BT * NCHUNK;
    float* rowterm = gold + BT;

    convert_bf16<<<dim3(2048), dim3(256), 0, stream>>>(Wt, Wb, (int)(nW / 8));
    convert_bf16<<<dim3(256), dim3(256), 0, stream>>>(X, Xb, (int)(nX / 8));
    gemm_lse_bf16<<<dim3(MT * NTT), dim3(256), 0, stream>>>(Wb, Xb, target,
                                                            bias, pM, pS, gold);
    reduce_lse<<<dim3(BT / 4), dim3(256), 0, stream>>>(pM, pS, gold, target,
                                                       lw, rowterm);
    finalize<<<dim3(1), dim3(256), 0, stream>>>(rowterm, target, rsw, gas, out);
  } else {
    float* pM = (float*)d_ws;
    float* pS = pM + (size_t)BT * NCHUNK;
    float* gold = pS + (size_t)BT * NCHUNK;
    float* rowterm = gold + BT;

    fused_gemm_lse<<<dim3(MT * NTT), dim3(256), 0, stream>>>(Wt, X, target,
                                                             bias, pM, pS, gold);
    reduce_lse<<<dim3(BT / 4), dim3(256), 0, stream>>>(pM, pS, gold, target,
                                                       lw, rowterm);
    finalize<<<dim3(1), dim3(256), 0, stream>>>(rowterm, target, rsw, gas, out);
  }
}

// Round 3
// 708.178 us; speedup vs baseline: 1.4824x; 1.3324x over previous
//
#include <hip/hip_runtime.h>
#include <hip/hip_bf16.h>
#include <math.h>

#define IGNORE_INDEX (-100)

constexpr int BT = 2048, H = 4096, V = 32000;
constexpr int BM = 256, BN = 256, BK = 64;
constexpr int KT = H / BK;            // 64 k-tiles
constexpr int MT2 = BT / BM;          // 8
constexpr int NT2 = V / BN;           // 125
constexpr int NCHUNK = NT2 * 4;       // 500 partial chunks/row (64 cols each)

typedef __bf16 bf16x8 __attribute__((ext_vector_type(8)));
typedef float f32x4 __attribute__((ext_vector_type(4)));

__device__ __forceinline__ void gload_lds16(const __bf16* g, short* l) {
  __builtin_amdgcn_global_load_lds(
      (const __attribute__((address_space(1))) unsigned int*)(g),
      (__attribute__((address_space(3))) unsigned int*)(l), 16, 0, 0);
}

// short index into one [256][32] K-half tile; 16B-slot XOR swizzle on
// (row>>1)&3 -> a 16-lane frag read covers all 32 banks (2-way = free).
__device__ __forceinline__ int kidx(int row, int j) {
  return row * 32 + (((j ^ ((row >> 1) & 3)) & 3) << 3);
}

#define BAR()        asm volatile("s_barrier" ::: "memory")
#define WAIT_LGKM0() asm volatile("s_waitcnt lgkmcnt(0)" ::: "memory")
#define WAIT_VM(N)   asm volatile("s_waitcnt vmcnt(" #N ")" ::: "memory")

// ---------------------------------------------------------------------------
// fp32 -> bf16 bulk convert
// ---------------------------------------------------------------------------
__global__ __launch_bounds__(256)
void convert_bf16(const float* __restrict__ src, __bf16* __restrict__ dst,
                  int n8) {
  int i = blockIdx.x * blockDim.x + threadIdx.x;
  const int stride = gridDim.x * blockDim.x;
  for (; i < n8; i += stride) {
    const float4 f0 = ((const float4*)src)[2 * i];
    const float4 f1 = ((const float4*)src)[2 * i + 1];
    bf16x8 v;
    v[0] = (__bf16)f0.x; v[1] = (__bf16)f0.y;
    v[2] = (__bf16)f0.z; v[3] = (__bf16)f0.w;
    v[4] = (__bf16)f1.x; v[5] = (__bf16)f1.y;
    v[6] = (__bf16)f1.z; v[7] = (__bf16)f1.w;
    ((bf16x8*)dst)[i] = v;
  }
}

// ---------------------------------------------------------------------------
// 256x256 8-phase bf16 MFMA GEMM (T2 swizzle + T3/T4 counted-vmcnt pipeline +
// T5 setprio) with fused bias + per-row partial-LSE epilogue.
// ---------------------------------------------------------------------------
__global__ __launch_bounds__(512, 2)
void gemm_lse_8ph(const __bf16* __restrict__ Wb,   // (V,H) bf16
                  const __bf16* __restrict__ Xb,   // (BT,H) bf16
                  const int* __restrict__ target,
                  const float* __restrict__ bias,
                  float* __restrict__ pM, float* __restrict__ pS,
                  float* __restrict__ gold)
{
  // [buf][khalf][256 rows][32 k-cols]  -> 4 x 16KB per operand = 128KB total
  __shared__ short As[2][2][256 * 32];
  __shared__ short Bs[2][2][256 * 32];

  const int tid  = threadIdx.x;
  const int lane = tid & 63;
  const int wid  = tid >> 6;
  const int wr   = wid >> 2;        // 0..1 : rows [wr*128, +128)
  const int wcol = wid & 3;         // 0..3 : cols [wcol*64, +64)

  // XCD swizzle: nwg = 1000 = 8*125, bijective
  const int bid = (int)blockIdx.x;
  const int swz = (bid & 7) * (1000 / 8) + (bid >> 3);
  const int mt = swz & (MT2 - 1);
  const int nt = swz >> 3;          // 8 consecutive swz share one W panel
  const int m0 = mt * BM, n0 = nt * BN;

  const int l15 = lane & 15;
  const int j4  = lane >> 4;
  // staging: lane covers row (l>>2) of its 16-row chunk, 16B slot (l&3);
  // source column pre-swizzled so linear LDS dest realizes the XOR layout
  const int srow = lane >> 2;
  const int sj8  = (((lane & 3) ^ ((lane >> 3) & 3)) << 3);

  f32x4 acc[8][4] = {};
  bf16x8 af[4], bfr[4];

#define STAGE_A(BUF, KH, KTI)                                                 \
  { _Pragma("unroll")                                                         \
    for (int q = 0; q < 2; ++q)                                               \
      gload_lds16(Xb + ((size_t)(m0 + (q * 8 + wid) * 16 + srow) * H +        \
                        (KTI) * BK + (KH) * 32 + sj8),                        \
                  &As[BUF][KH][(q * 8 + wid) * 512]); }

#define STAGE_B(BUF, KH, KTI)                                                 \
  { _Pragma("unroll")                                                         \
    for (int q = 0; q < 2; ++q)                                               \
      gload_lds16(Wb + ((size_t)(n0 + (q * 8 + wid) * 16 + srow) * H +        \
                        (KTI) * BK + (KH) * 32 + sj8),                        \
                  &Bs[BUF][KH][(q * 8 + wid) * 512]); }

#define READ_A(BUF, KH, MH)                                                   \
  { _Pragma("unroll")                                                         \
    for (int mi = 0; mi < 4; ++mi)                                            \
      af[mi] = *(const bf16x8*)                                               \
          &As[BUF][KH][kidx(wr * 128 + (MH) * 64 + mi * 16 + l15, j4)]; }

#define READ_B(BUF, KH)                                                       \
  { _Pragma("unroll")                                                         \
    for (int ni = 0; ni < 4; ++ni)                                            \
      bfr[ni] = *(const bf16x8*)                                              \
          &Bs[BUF][KH][kidx(wcol * 64 + ni * 16 + l15, j4)]; }

#define MFMA16(MH)                                                            \
  { __builtin_amdgcn_s_setprio(1);                                            \
    _Pragma("unroll")                                                         \
    for (int mi = 0; mi < 4; ++mi)                                            \
      _Pragma("unroll")                                                       \
      for (int ni = 0; ni < 4; ++ni)                                          \
        acc[(MH) * 4 + mi][ni] = __builtin_amdgcn_mfma_f32_16x16x32_bf16(     \
            af[mi], bfr[ni], acc[(MH) * 4 + mi][ni], 0, 0, 0);                \
    __builtin_amdgcn_s_setprio(0); }

  // ---- prologue: tile0 fully + tile1 {B.k0, A.k0, B.k1} (A.k1 comes in P1)
  STAGE_B(0, 0, 0); STAGE_A(0, 0, 0); STAGE_B(0, 1, 0); STAGE_A(0, 1, 0);
  STAGE_B(1, 0, 1); STAGE_A(1, 0, 1); STAGE_B(1, 1, 1);
  WAIT_VM(6);                       // tile0's 8 loads landed; 6 in flight
  BAR();

  // ---- main loop: 2 K-tiles / iteration, 8 phases. Every stage overwrites a
  // region whose LAST ds_read completed >=1 barrier before the stage issues.
  for (int t = 0; t <= KT - 4; t += 2) {
    // P1: compute t(kk0,mh0); stage (t+1).A.k1
    READ_A(0, 0, 0); READ_B(0, 0); STAGE_A(1, 1, t + 1);
    BAR(); WAIT_LGKM0(); MFMA16(0); BAR();
    // P2: t(kk0,mh1); stage (t+2).B.k0  [Bs00 last read P1]
    READ_A(0, 0, 1); STAGE_B(0, 0, t + 2);
    BAR(); WAIT_LGKM0(); MFMA16(1); BAR();
    // P3: t(kk1,mh0); stage (t+2).A.k0  [As00 last read P2]
    READ_A(0, 1, 0); READ_B(0, 1); STAGE_A(0, 0, t + 2);
    BAR(); WAIT_LGKM0(); MFMA16(0); BAR();
    // P4: t(kk1,mh1); stage (t+2).B.k1  [Bs01 last read P3]; vmcnt(6) -> all
    // of tile t+1 landed before P5's reads
    READ_A(0, 1, 1); STAGE_B(0, 1, t + 2);
    BAR(); WAIT_LGKM0(); MFMA16(1); WAIT_VM(6); BAR();
    // P5: t+1(kk0,mh0); stage (t+2).A.k1  [As01 last read P4]
    READ_A(1, 0, 0); READ_B(1, 0); STAGE_A(0, 1, t + 2);
    BAR(); WAIT_LGKM0(); MFMA16(0); BAR();
    // P6: t+1(kk0,mh1); stage (t+3).B.k0  [Bs10 last read P5]
    READ_A(1, 0, 1); STAGE_B(1, 0, t + 3);
    BAR(); WAIT_LGKM0(); MFMA16(1); BAR();
    // P7: t+1(kk1,mh0); stage (t+3).A.k0  [As10 last read P6]
    READ_A(1, 1, 0); READ_B(1, 1); STAGE_A(1, 0, t + 3);
    BAR(); WAIT_LGKM0(); MFMA16(0); BAR();
    // P8: t+1(kk1,mh1); stage (t+3).B.k1  [Bs11 last read P7]; vmcnt(6) ->
    // all of tile t+2 landed before next P1
    READ_A(1, 1, 1); STAGE_B(1, 1, t + 3);
    BAR(); WAIT_LGKM0(); MFMA16(1); WAIT_VM(6); BAR();
  }

  // ---- tail: tiles KT-2, KT-1 (no further staging)
  READ_A(0, 0, 0); READ_B(0, 0); STAGE_A(1, 1, KT - 1);
  BAR(); WAIT_LGKM0(); MFMA16(0); BAR();
  READ_A(0, 0, 1);
  BAR(); WAIT_LGKM0(); MFMA16(1); BAR();
  READ_A(0, 1, 0); READ_B(0, 1);
  BAR(); WAIT_LGKM0(); MFMA16(0); BAR();
  READ_A(0, 1, 1);
  BAR(); WAIT_LGKM0(); MFMA16(1); WAIT_VM(0); BAR();
  READ_A(1, 0, 0); READ_B(1, 0);
  BAR(); WAIT_LGKM0(); MFMA16(0); BAR();
  READ_A(1, 0, 1);
  BAR(); WAIT_LGKM0(); MFMA16(1); BAR();
  READ_A(1, 1, 0); READ_B(1, 1);
  BAR(); WAIT_LGKM0(); MFMA16(0); BAR();
  READ_A(1, 1, 1);
  BAR(); WAIT_LGKM0(); MFMA16(1);

#undef STAGE_A
#undef STAGE_B
#undef READ_A
#undef READ_B
#undef MFMA16

  // ---- epilogue: bias + per-row (max, sum-exp) over this wave's 64 cols
  const int g = lane >> 4;          // row group 0..3
  const int c = lane & 15;          // col-in-fragment
  const int colbase = n0 + wcol * 64;
  float bv[4];
#pragma unroll
  for (int ni = 0; ni < 4; ++ni) bv[ni] = bias[colbase + ni * 16 + c];

  const int chunk = nt * 4 + wcol;
#pragma unroll
  for (int mi = 0; mi < 8; ++mi) {
#pragma unroll
    for (int r = 0; r < 4; ++r) {
      const int row = m0 + wr * 128 + mi * 16 + g * 4 + r;
      const float v0 = acc[mi][0][r] + bv[0];
      const float v1 = acc[mi][1][r] + bv[1];
      const float v2 = acc[mi][2][r] + bv[2];
      const float v3 = acc[mi][3][r] + bv[3];
      float mx = fmaxf(fmaxf(v0, v1), fmaxf(v2, v3));
#pragma unroll
      for (int d = 1; d < 16; d <<= 1) mx = fmaxf(mx, __shfl_xor(mx, d));
      float s = expf(v0 - mx) + expf(v1 - mx) + expf(v2 - mx) + expf(v3 - mx);
#pragma unroll
      for (int d = 1; d < 16; d <<= 1) s += __shfl_xor(s, d);
      if (c == 0) {
        pM[(size_t)row * NCHUNK + chunk] = mx;
        pS[(size_t)row * NCHUNK + chunk] = s;
      }
      const int t = target[row];
      const int d0 = t - colbase;
      if (d0 >= 0 && d0 < 64 && c == (d0 & 15)) {
        const int nw = d0 >> 4;
        const float gv = (nw == 0) ? v0 : (nw == 1) ? v1 : (nw == 2) ? v2 : v3;
        gold[row] = gv;
      }
    }
  }
}

// one wave per row: combine 500 (max, sumexp) chunks -> rowterm
__global__ __launch_bounds__(256)
void reduce_lse(const float* __restrict__ pM, const float* __restrict__ pS,
                const float* __restrict__ gold, const int* __restrict__ target,
                const float* __restrict__ lw, float* __restrict__ rowterm)
{
  const int wid = threadIdx.x >> 6, lane = threadIdx.x & 63;
  const int row = blockIdx.x * 4 + wid;
  if (row >= BT) return;
  const float* pm = pM + (size_t)row * NCHUNK;
  const float* ps = pS + (size_t)row * NCHUNK;
  float m = -INFINITY;
  for (int c2 = lane; c2 < NCHUNK; c2 += 64) m = fmaxf(m, pm[c2]);
#pragma unroll
  for (int d = 1; d < 64; d <<= 1) m = fmaxf(m, __shfl_xor(m, d));
  float s = 0.f;
  for (int c2 = lane; c2 < NCHUNK; c2 += 64) s += ps[c2] * expf(pm[c2] - m);
#pragma unroll
  for (int d = 1; d < 64; d <<= 1) s += __shfl_xor(s, d);
  if (lane == 0) {
    const int t = target[row];
    float term = 0.f;
    if (t != IGNORE_INDEX) term = (m + logf(s) - gold[row]) * lw[row];
    rowterm[row] = term;
  }
}

// single-block deterministic finalize
__global__ __launch_bounds__(256)
void finalize(const float* __restrict__ rowterm, const int* __restrict__ target,
              const float* __restrict__ rsw, const int* __restrict__ gas,
              float* __restrict__ out)
{
  __shared__ float sred[4];
  __shared__ int cred[4];
  const int tid = threadIdx.x;
  float s = 0.f;
  int cnt = 0;
  for (int i = tid; i < BT; i += 256) {
    s += rowterm[i];
    cnt += (target[i] != IGNORE_INDEX) ? 1 : 0;
  }
#pragma unroll
  for (int d = 1; d < 64; d <<= 1) {
    s += __shfl_xor(s, d);
    cnt += __shfl_xor(cnt, d);
  }
  const int wid = tid >> 6, lane = tid & 63;
  if (lane == 0) { sred[wid] = s; cred[wid] = cnt; }
  __syncthreads();
  if (tid == 0) {
    const float st = sred[0] + sred[1] + sred[2] + sred[3];
    const int ct = cred[0] + cred[1] + cred[2] + cred[3];
    const float n = (float)((ct > 0) ? ct : 1);
    const float rs = rsw[0];
    float loss = (rs == 0.f) ? 0.f : (st / n) / rs;
    loss /= (float)gas[0];
    out[0] = loss;
  }
}

extern "C" void kernel_launch(void* const* d_in, const int* in_sizes, int n_in,
                              void* d_out, int out_size, void* d_ws, size_t ws_size,
                              hipStream_t stream)
{
  const float* Wt     = (const float*)d_in[0];  // lin_weight (V,H)
  const float* X      = (const float*)d_in[1];  // _input (BT,H)
  const int*   target = (const int*)d_in[2];
  const float* bias   = (const float*)d_in[3];
  const float* lw     = (const float*)d_in[4];
  const float* rsw    = (const float*)d_in[5];
  const int*   gas    = (const int*)d_in[6];
  float* out = (float*)d_out;

  const size_t nW = (size_t)V * H, nX = (size_t)BT * H;

  __bf16* Wb = (__bf16*)d_ws;
  __bf16* Xb = Wb + nW;
  float* pM = (float*)(Xb + nX);
  float* pS = pM + (size_t)BT * NCHUNK;
  float* gold = pS + (size_t)BT * NCHUNK;
  float* rowterm = gold + BT;

  convert_bf16<<<dim3(2048), dim3(256), 0, stream>>>(Wt, Wb, (int)(nW / 8));
  convert_bf16<<<dim3(256), dim3(256), 0, stream>>>(X, Xb, (int)(nX / 8));
  gemm_lse_8ph<<<dim3(MT2 * NT2), dim3(512), 0, stream>>>(Wb, Xb, target,
                                                          bias, pM, pS, gold);
  reduce_lse<<<dim3(BT / 4), dim3(256), 0, stream>>>(pM, pS, gold, target, lw,
                                                     rowterm);
  finalize<<<dim3(1), dim3(256), 0, stream>>>(rowterm, target, rsw, gas, out);
}

// Round 4
// 688.372 us; speedup vs baseline: 1.5250x; 1.0288x over previous
//
#include <hip/hip_runtime.h>
#include <hip/hip_bf16.h>
#include <math.h>

#define IGNORE_INDEX (-100)

constexpr int BT = 2048, H = 4096, V = 32000;
constexpr int BM = 256, BN = 256, BK = 64;
constexpr int KT = H / BK;            // 64 k-tiles
constexpr int MT2 = BT / BM;          // 8
constexpr int NT2 = V / BN;           // 125
constexpr int NCHUNK = NT2 * 4;       // 500 partial chunks/row (64 cols each)

typedef __bf16 bf16x8 __attribute__((ext_vector_type(8)));
typedef float f32x4 __attribute__((ext_vector_type(4)));

__device__ __forceinline__ void gload_lds16(const __bf16* g, short* l) {
  __builtin_amdgcn_global_load_lds(
      (const __attribute__((address_space(1))) unsigned int*)(g),
      (__attribute__((address_space(3))) unsigned int*)(l), 16, 0, 0);
}

#define BAR()        asm volatile("s_barrier" ::: "memory")
#define WAIT_LGKM0() asm volatile("s_waitcnt lgkmcnt(0)" ::: "memory")
#define WAIT_VM(N)   asm volatile("s_waitcnt vmcnt(" #N ")" ::: "memory")

// ---------------------------------------------------------------------------
// fp32 -> bf16 bulk convert
// ---------------------------------------------------------------------------
__global__ __launch_bounds__(256)
void convert_bf16(const float* __restrict__ src, __bf16* __restrict__ dst,
                  int n8) {
  int i = blockIdx.x * blockDim.x + threadIdx.x;
  const int stride = gridDim.x * blockDim.x;
  for (; i < n8; i += stride) {
    const float4 f0 = ((const float4*)src)[2 * i];
    const float4 f1 = ((const float4*)src)[2 * i + 1];
    bf16x8 v;
    v[0] = (__bf16)f0.x; v[1] = (__bf16)f0.y;
    v[2] = (__bf16)f0.z; v[3] = (__bf16)f0.w;
    v[4] = (__bf16)f1.x; v[5] = (__bf16)f1.y;
    v[6] = (__bf16)f1.z; v[7] = (__bf16)f1.w;
    ((bf16x8*)dst)[i] = v;
  }
}

// ---------------------------------------------------------------------------
// 256x256 8-phase bf16 MFMA GEMM, 1-barrier-per-phase variant.
// Invariant: a stage at phase p targets a region whose last reader is at
// phase p-2 (reads drain at lgkmcnt(0) after BAR(q); BAR(q+1) separates the
// drain from the stage). vmcnt(4) at P4/P8 guarantees landing deadlines
// (audited per-region: A11@P2->read P7, A01@P6->read next P3, etc.).
// LDS addressing: swizzle slot is lane-only -> all ds_read addresses are
// one per-lane base + compile-time immediate.
// ---------------------------------------------------------------------------
__global__ __launch_bounds__(512, 2)
void gemm_lse_8ph(const __bf16* __restrict__ Wb,   // (V,H) bf16
                  const __bf16* __restrict__ Xb,   // (BT,H) bf16
                  const int* __restrict__ target,
                  const float* __restrict__ bias,
                  float* __restrict__ pM, float* __restrict__ pS,
                  float* __restrict__ gold)
{
  // flat: [buf][kh][256*32] shorts; buf stride 16384, kh stride 8192
  __shared__ short As[4 * 8192];
  __shared__ short Bs[4 * 8192];

  const int tid  = threadIdx.x;
  const int lane = tid & 63;
  const int wid  = tid >> 6;
  const int wr   = wid >> 2;        // 0..1 : rows [wr*128, +128)
  const int wcol = wid & 3;         // 0..3 : cols [wcol*64, +64)

  // XCD swizzle: nwg = 1000 = 8*125, bijective
  const int bid = (int)blockIdx.x;
  const int swz = (bid & 7) * 125 + (bid >> 3);
  const int mt = swz & (MT2 - 1);
  const int nt = swz >> 3;
  const int m0 = mt * BM, n0 = nt * BN;

  const int l15 = lane & 15;
  const int j4  = lane >> 4;
  // swizzle slot is lane-only: (row>>1)&3 == (l15>>1)&3 for all frag rows
  const int slotx = ((j4 ^ ((l15 >> 1) & 3)) & 3) << 3;      // shorts
  const int abase = (wr * 128 + l15) * 32 + slotx;
  const int bbase = (wcol * 64 + l15) * 32 + slotx;

  // staging: lane covers row (l>>2), 16B slot (l&3); source pre-swizzled
  const int srow = lane >> 2;
  const int sj8  = (((lane & 3) ^ ((lane >> 3) & 3)) << 3);

  const __bf16* ax0 = Xb + (size_t)(m0 + wid * 16 + srow) * H + sj8;
  const __bf16* ax1 = ax0 + (size_t)128 * H;
  const __bf16* bx0 = Wb + (size_t)(n0 + wid * 16 + srow) * H + sj8;
  const __bf16* bx1 = bx0 + (size_t)128 * H;

  f32x4 acc[8][4] = {};
  bf16x8 af[4], bfr[4];

#define STAGE_A(BUF, KH, DT)                                                  \
  { gload_lds16(ax0 + (DT) * BK + (KH) * 32,                                  \
                &As[(BUF) * 16384 + (KH) * 8192 + wid * 512]);                \
    gload_lds16(ax1 + (DT) * BK + (KH) * 32,                                  \
                &As[(BUF) * 16384 + (KH) * 8192 + (8 + wid) * 512]); }

#define STAGE_B(BUF, KH, DT)                                                  \
  { gload_lds16(bx0 + (DT) * BK + (KH) * 32,                                  \
                &Bs[(BUF) * 16384 + (KH) * 8192 + wid * 512]);                \
    gload_lds16(bx1 + (DT) * BK + (KH) * 32,                                  \
                &Bs[(BUF) * 16384 + (KH) * 8192 + (8 + wid) * 512]); }

#define READ_A(BUF, KH, MH)                                                   \
  { _Pragma("unroll")                                                         \
    for (int mi = 0; mi < 4; ++mi)                                            \
      af[mi] = *(const bf16x8*)&As[(BUF) * 16384 + (KH) * 8192 + abase +      \
                                   (MH) * 2048 + mi * 512]; }

#define READ_B(BUF, KH)                                                       \
  { _Pragma("unroll")                                                         \
    for (int ni = 0; ni < 4; ++ni)                                            \
      bfr[ni] = *(const bf16x8*)&Bs[(BUF) * 16384 + (KH) * 8192 + bbase +     \
                                    ni * 512]; }

#define MFMA16(MH)                                                            \
  { __builtin_amdgcn_s_setprio(1);                                            \
    _Pragma("unroll")                                                         \
    for (int mi = 0; mi < 4; ++mi)                                            \
      _Pragma("unroll")                                                       \
      for (int ni = 0; ni < 4; ++ni)                                          \
        acc[(MH) * 4 + mi][ni] = __builtin_amdgcn_mfma_f32_16x16x32_bf16(     \
            af[mi], bfr[ni], acc[(MH) * 4 + mi][ni], 0, 0, 0);                \
    __builtin_amdgcn_s_setprio(0); }

  // ---- prologue: tile0 fully + tile1 k0.  VM(4) leaves {B10,A10} in flight
  // (drained at first P4's VM(4) before P5 reads them).
  STAGE_B(0, 0, 0); STAGE_A(0, 0, 0); STAGE_B(0, 1, 0); STAGE_A(0, 1, 0);
  STAGE_B(1, 0, 1); STAGE_A(1, 0, 1);
  WAIT_VM(4);
  BAR();

  // ---- main loop: 2 K-tiles/iter, 8 phases, ONE barrier each
  for (int t = 0; t <= KT - 4; t += 2) {
    // P1: compute t(k0,mh0); stage B11 <- (t+1).k1   [B11 drained prev P8]
    READ_A(0, 0, 0); READ_B(0, 0); STAGE_B(1, 1, 1);
    BAR(); WAIT_LGKM0(); MFMA16(0);
    // P2: t(k0,mh1); stage A11 <- (t+1).k1           [A11 drained prev P8+BAR(P1)]
    READ_A(0, 0, 1); STAGE_A(1, 1, 1);
    BAR(); WAIT_LGKM0(); MFMA16(1);
    // P3: t(k1,mh0); stage B00 <- (t+2).k0           [B00 last read P1]
    READ_A(0, 1, 0); READ_B(0, 1); STAGE_B(0, 0, 2);
    BAR(); WAIT_LGKM0(); MFMA16(0);
    // P4: t(k1,mh1); stage A00 <- (t+2).k0; VM(4) drains through P2's A11
    READ_A(0, 1, 1); STAGE_A(0, 0, 2);
    WAIT_VM(4); BAR(); WAIT_LGKM0(); MFMA16(1);
    // P5: t+1(k0,mh0); stage B01 <- (t+2).k1         [B01 last read P3]
    READ_A(1, 0, 0); READ_B(1, 0); STAGE_B(0, 1, 2);
    BAR(); WAIT_LGKM0(); MFMA16(0);
    // P6: t+1(k0,mh1); stage A01 <- (t+2).k1         [A01 last read P4]
    READ_A(1, 0, 1); STAGE_A(0, 1, 2);
    BAR(); WAIT_LGKM0(); MFMA16(1);
    // P7: t+1(k1,mh0); stage B10 <- (t+3).k0         [B10 last read P5]
    READ_A(1, 1, 0); READ_B(1, 1); STAGE_B(1, 0, 3);
    BAR(); WAIT_LGKM0(); MFMA16(0);
    // P8: t+1(k1,mh1); stage A10 <- (t+3).k0; VM(4) drains through P6's A01
    READ_A(1, 1, 1); STAGE_A(1, 0, 3);
    WAIT_VM(4); BAR(); WAIT_LGKM0(); MFMA16(1);

    ax0 += 2 * BK; ax1 += 2 * BK; bx0 += 2 * BK; bx1 += 2 * BK;
  }

  // ---- tail: tiles KT-2 (buf0), KT-1 (buf1); stage only B11/A11 <- KT-1.k1
  READ_A(0, 0, 0); READ_B(0, 0); STAGE_B(1, 1, 1);
  BAR(); WAIT_LGKM0(); MFMA16(0);
  READ_A(0, 0, 1); STAGE_A(1, 1, 1);
  BAR(); WAIT_LGKM0(); MFMA16(1);
  READ_A(0, 1, 0); READ_B(0, 1);
  WAIT_LGKM0(); MFMA16(0);
  READ_A(0, 1, 1);
  WAIT_VM(0); BAR(); WAIT_LGKM0(); MFMA16(1);
  READ_A(1, 0, 0); READ_B(1, 0);
  WAIT_LGKM0(); MFMA16(0);
  READ_A(1, 0, 1);
  WAIT_LGKM0(); MFMA16(1);
  READ_A(1, 1, 0); READ_B(1, 1);
  WAIT_LGKM0(); MFMA16(0);
  READ_A(1, 1, 1);
  WAIT_LGKM0(); MFMA16(1);

#undef STAGE_A
#undef STAGE_B
#undef READ_A
#undef READ_B
#undef MFMA16

  // ---- epilogue: bias + per-row (max, sum-exp) over this wave's 64 cols
  const int g = lane >> 4;          // row group 0..3
  const int c = lane & 15;          // col-in-fragment
  const int colbase = n0 + wcol * 64;
  float bv[4];
#pragma unroll
  for (int ni = 0; ni < 4; ++ni) bv[ni] = bias[colbase + ni * 16 + c];

  const int chunk = nt * 4 + wcol;
#pragma unroll
  for (int mi = 0; mi < 8; ++mi) {
#pragma unroll
    for (int r = 0; r < 4; ++r) {
      const int row = m0 + wr * 128 + mi * 16 + g * 4 + r;
      const float v0 = acc[mi][0][r] + bv[0];
      const float v1 = acc[mi][1][r] + bv[1];
      const float v2 = acc[mi][2][r] + bv[2];
      const float v3 = acc[mi][3][r] + bv[3];
      float mx = fmaxf(fmaxf(v0, v1), fmaxf(v2, v3));
#pragma unroll
      for (int d = 1; d < 16; d <<= 1) mx = fmaxf(mx, __shfl_xor(mx, d));
      float s = expf(v0 - mx) + expf(v1 - mx) + expf(v2 - mx) + expf(v3 - mx);
#pragma unroll
      for (int d = 1; d < 16; d <<= 1) s += __shfl_xor(s, d);
      if (c == 0) {
        pM[(size_t)row * NCHUNK + chunk] = mx;
        pS[(size_t)row * NCHUNK + chunk] = s;
      }
      const int t = target[row];
      const int d0 = t - colbase;
      if (d0 >= 0 && d0 < 64 && c == (d0 & 15)) {
        const int nw = d0 >> 4;
        const float gv = (nw == 0) ? v0 : (nw == 1) ? v1 : (nw == 2) ? v2 : v3;
        gold[row] = gv;
      }
    }
  }
}

// one wave per row: combine 500 (max, sumexp) chunks -> rowterm
__global__ __launch_bounds__(256)
void reduce_lse(const float* __restrict__ pM, const float* __restrict__ pS,
                const float* __restrict__ gold, const int* __restrict__ target,
                const float* __restrict__ lw, float* __restrict__ rowterm)
{
  const int wid = threadIdx.x >> 6, lane = threadIdx.x & 63;
  const int row = blockIdx.x * 4 + wid;
  if (row >= BT) return;
  const float* pm = pM + (size_t)row * NCHUNK;
  const float* ps = pS + (size_t)row * NCHUNK;
  float m = -INFINITY;
  for (int c2 = lane; c2 < NCHUNK; c2 += 64) m = fmaxf(m, pm[c2]);
#pragma unroll
  for (int d = 1; d < 64; d <<= 1) m = fmaxf(m, __shfl_xor(m, d));
  float s = 0.f;
  for (int c2 = lane; c2 < NCHUNK; c2 += 64) s += ps[c2] * expf(pm[c2] - m);
#pragma unroll
  for (int d = 1; d < 64; d <<= 1) s += __shfl_xor(s, d);
  if (lane == 0) {
    const int t = target[row];
    float term = 0.f;
    if (t != IGNORE_INDEX) term = (m + logf(s) - gold[row]) * lw[row];
    rowterm[row] = term;
  }
}

// single-block deterministic finalize
__global__ __launch_bounds__(256)
void finalize(const float* __restrict__ rowterm, const int* __restrict__ target,
              const float* __restrict__ rsw, const int* __restrict__ gas,
              float* __restrict__ out)
{
  __shared__ float sred[4];
  __shared__ int cred[4];
  const int tid = threadIdx.x;
  float s = 0.f;
  int cnt = 0;
  for (int i = tid; i < BT; i += 256) {
    s += rowterm[i];
    cnt += (target[i] != IGNORE_INDEX) ? 1 : 0;
  }
#pragma unroll
  for (int d = 1; d < 64; d <<= 1) {
    s += __shfl_xor(s, d);
    cnt += __shfl_xor(cnt, d);
  }
  const int wid = tid >> 6, lane = tid & 63;
  if (lane == 0) { sred[wid] = s; cred[wid] = cnt; }
  __syncthreads();
  if (tid == 0) {
    const float st = sred[0] + sred[1] + sred[2] + sred[3];
    const int ct = cred[0] + cred[1] + cred[2] + cred[3];
    const float n = (float)((ct > 0) ? ct : 1);
    const float rs = rsw[0];
    float loss = (rs == 0.f) ? 0.f : (st / n) / rs;
    loss /= (float)gas[0];
    out[0] = loss;
  }
}

extern "C" void kernel_launch(void* const* d_in, const int* in_sizes, int n_in,
                              void* d_out, int out_size, void* d_ws, size_t ws_size,
                              hipStream_t stream)
{
  const float* Wt     = (const float*)d_in[0];  // lin_weight (V,H)
  const float* X      = (const float*)d_in[1];  // _input (BT,H)
  const int*   target = (const int*)d_in[2];
  const float* bias   = (const float*)d_in[3];
  const float* lw     = (const float*)d_in[4];
  const float* rsw    = (const float*)d_in[5];
  const int*   gas    = (const int*)d_in[6];
  float* out = (float*)d_out;

  const size_t nW = (size_t)V * H, nX = (size_t)BT * H;

  __bf16* Wb = (__bf16*)d_ws;
  __bf16* Xb = Wb + nW;
  float* pM = (float*)(Xb + nX);
  float* pS = pM + (size_t)BT * NCHUNK;
  float* gold = pS + (size_t)BT * NCHUNK;
  float* rowterm = gold + BT;

  convert_bf16<<<dim3(2048), dim3(256), 0, stream>>>(Wt, Wb, (int)(nW / 8));
  convert_bf16<<<dim3(256), dim3(256), 0, stream>>>(X, Xb, (int)(nX / 8));
  gemm_lse_8ph<<<dim3(MT2 * NT2), dim3(512), 0, stream>>>(Wb, Xb, target,
                                                          bias, pM, pS, gold);
  reduce_lse<<<dim3(BT / 4), dim3(256), 0, stream>>>(pM, pS, gold, target, lw,
                                                     rowterm);
  finalize<<<dim3(1), dim3(256), 0, stream>>>(rowterm, target, rsw, gas, out);
}